// Round 2
// baseline (630.774 us; speedup 1.0000x reference)
//
#include <hip/hip_runtime.h>
#include <math.h>

typedef unsigned short u16;
typedef unsigned int u32;
typedef __bf16 bf16x8 __attribute__((ext_vector_type(8)));
typedef float f32x4 __attribute__((ext_vector_type(4)));
typedef u16 u16x4 __attribute__((ext_vector_type(4)));
typedef u16 u16x8 __attribute__((ext_vector_type(8)));

#define MFMA16(a, b, c) __builtin_amdgcn_mfma_f32_16x16x32_bf16((a), (b), (c), 0, 0, 0)

#define GLL16(g, l)                                                   \
  __builtin_amdgcn_global_load_lds(                                   \
      (const __attribute__((address_space(1))) void*)(g),             \
      (__attribute__((address_space(3))) void*)(l), 16, 0, 0)

__device__ __forceinline__ u16 f2bf(float f) {
  u32 u = __builtin_bit_cast(u32, f);
  u32 r = (u + 0x7fffu + ((u >> 16) & 1u)) >> 16;
  return (u16)r;
}

// ---------------------------------------------------------------------------
// fp32 -> bf16 elementwise convert (n multiple of 1024*4 assumed by grid)
// ---------------------------------------------------------------------------
__global__ __launch_bounds__(256) void cvt_f32_bf16(const float* __restrict__ in,
                                                    u16* __restrict__ out) {
  size_t i = ((size_t)blockIdx.x * 256 + threadIdx.x) * 4;
  float4 v = *(const float4*)(in + i);
  u16x4 o;
  o[0] = f2bf(v.x); o[1] = f2bf(v.y); o[2] = f2bf(v.z); o[3] = f2bf(v.w);
  *(u16x4*)(out + i) = o;
}

// ---------------------------------------------------------------------------
// fp32 in[R][Cn] -> bf16 out[Cn][R] (64x64 tiles, fused convert+transpose)
// ---------------------------------------------------------------------------
__global__ __launch_bounds__(256) void transpose_w(const float* __restrict__ in,
                                                   u16* __restrict__ out,
                                                   int R, int Cn) {
  __shared__ u16 tile[64][72];
  const int t = threadIdx.x;
  const int tr = blockIdx.y * 64;
  const int tc = blockIdx.x * 64;
#pragma unroll
  for (int p = 0; p < 4; ++p) {
    int chunk = p * 256 + t;
    int r = chunk >> 4, cq = chunk & 15;
    float4 v = *(const float4*)(in + (size_t)(tr + r) * Cn + tc + cq * 4);
    tile[r][cq * 4 + 0] = f2bf(v.x);
    tile[r][cq * 4 + 1] = f2bf(v.y);
    tile[r][cq * 4 + 2] = f2bf(v.z);
    tile[r][cq * 4 + 3] = f2bf(v.w);
  }
  __syncthreads();
#pragma unroll
  for (int p = 0; p < 2; ++p) {
    int chunk = p * 256 + t;
    int c = chunk >> 3, rg = chunk & 7;
    u16x8 v;
#pragma unroll
    for (int i = 0; i < 8; ++i) v[i] = tile[rg * 8 + i][c];
    *(u16x8*)(out + (size_t)(tc + c) * R + tr + rg * 8) = v;
  }
}

// ---------------------------------------------------------------------------
// V-part transpose (bf16 S): VT[(b*16+h)*64 + d][l] = S[b*2048+l][2048+h*64+d]
// grid: x = l-tile (32), y = bh (64)
// ---------------------------------------------------------------------------
__global__ __launch_bounds__(256) void transpose_v(const u16* __restrict__ S,
                                                   u16* __restrict__ VT) {
  __shared__ u16 tile[64][72];
  const int t = threadIdx.x;
  const int lt = blockIdx.x;
  const int bh = blockIdx.y;
  const int b = bh >> 4, h = bh & 15;
  const u16* src = S + ((size_t)b * 2048 + (size_t)lt * 64) * 3072 + 2048 + h * 64;
  u16* dst = VT + (size_t)bh * 64 * 2048 + (size_t)lt * 64;
#pragma unroll
  for (int p = 0; p < 2; ++p) {
    int chunk = p * 256 + t;
    int r = chunk >> 3, cg = chunk & 7;
    u16x8 v = *(const u16x8*)(src + (size_t)r * 3072 + cg * 8);
    *(u16x8*)(&tile[r][cg * 8]) = v;
  }
  __syncthreads();
#pragma unroll
  for (int p = 0; p < 2; ++p) {
    int chunk = p * 256 + t;
    int d = chunk >> 3, rg = chunk & 7;
    u16x8 v;
#pragma unroll
    for (int i = 0; i < 8; ++i) v[i] = tile[rg * 8 + i][d];
    *(u16x8*)(dst + (size_t)d * 2048 + rg * 8) = v;
  }
}

// ---------------------------------------------------------------------------
// C[M][N] = A[M][K] @ B[K][N], BT = B^T as [N][K]. bf16 in, fp32 accum,
// output bf16 or fp32 (OUTF32). 128x128 tile, BK=64, 4 waves (2x2),
// global_load_lds staging w/ both-sides XOR swizzle (rule #21).
// ---------------------------------------------------------------------------
template <bool OUTF32>
__global__ __launch_bounds__(256, 2) void gemm_bt(const u16* __restrict__ A,
                                                  const u16* __restrict__ BT,
                                                  void* __restrict__ Cp,
                                                  int M, int N, int K) {
  __shared__ u16 As[128 * 64];
  __shared__ u16 Bs[128 * 64];
  const int tid = threadIdx.x;
  const int lane = tid & 63;
  const int wid = tid >> 6;
  const int wr = wid >> 1, wc = wid & 1;
  const int rl = lane & 15, kg = lane >> 4;
  const size_t rowA0 = (size_t)blockIdx.y * 128;
  const size_t rowB0 = (size_t)blockIdx.x * 128;

  const int r_st = tid >> 3;
  const int cg_st = tid & 7;

  f32x4 acc[4][4] = {};

  for (int kb = 0; kb < K; kb += 64) {
    __syncthreads();
#pragma unroll
    for (int it = 0; it < 4; ++it) {
      int r = it * 32 + r_st;
      int cgs = cg_st ^ (r & 7);  // inverse-swizzled global source
      GLL16(A + (rowA0 + r) * K + kb + cgs * 8, As + (size_t)r * 64 + cg_st * 8);
      GLL16(BT + (rowB0 + r) * K + kb + cgs * 8, Bs + (size_t)r * 64 + cg_st * 8);
    }
    __syncthreads();

    bf16x8 af[2][4], bfr[2][4];
#pragma unroll
    for (int kk = 0; kk < 2; ++kk) {
      int c8 = kk * 4 + kg;
#pragma unroll
      for (int m = 0; m < 4; ++m) {
        int ra = wr * 64 + m * 16 + rl;
        af[kk][m] = *(const bf16x8*)(As + (size_t)ra * 64 + (size_t)((c8 ^ (ra & 7)) * 8));
        int rb = wc * 64 + m * 16 + rl;
        bfr[kk][m] = *(const bf16x8*)(Bs + (size_t)rb * 64 + (size_t)((c8 ^ (rb & 7)) * 8));
      }
    }
#pragma unroll
    for (int kk = 0; kk < 2; ++kk)
#pragma unroll
      for (int m = 0; m < 4; ++m)
#pragma unroll
        for (int n = 0; n < 4; ++n)
          acc[m][n] = MFMA16(af[kk][m], bfr[kk][n], acc[m][n]);
  }

#pragma unroll
  for (int m = 0; m < 4; ++m)
#pragma unroll
    for (int n = 0; n < 4; ++n)
#pragma unroll
      for (int j = 0; j < 4; ++j) {
        size_t r = rowA0 + wr * 64 + m * 16 + kg * 4 + j;
        size_t c = rowB0 + wc * 64 + n * 16 + rl;
        if constexpr (OUTF32)
          ((float*)Cp)[r * N + c] = acc[m][n][j];
        else
          ((u16*)Cp)[r * N + c] = f2bf(acc[m][n][j]);
      }
}

// ---------------------------------------------------------------------------
// Causal flash attention. grid: x = q-block (32, 64 rows each), y = bh (64).
// 4 independent waves x 16 q-rows. Q,K from S (row stride 3072), V from VT.
// ---------------------------------------------------------------------------
__global__ __launch_bounds__(256, 2) void attn(const u16* __restrict__ S,
                                               const u16* __restrict__ VT,
                                               u16* __restrict__ Y) {
  __shared__ u16 P[4][16][72];  // per-wave P tile (padded: 2-way conflicts only)
  const int qblk = blockIdx.x;
  const int bh = blockIdx.y;
  const int b = bh >> 4, h = bh & 15;
  const int tid = threadIdx.x, lane = tid & 63, wid = tid >> 6;
  const int rl = lane & 15, kg = lane >> 4;
  const u16* Sq = S + (size_t)b * 2048 * 3072 + h * 64;
  const u16* Sk = Sq + 1024;
  const u16* Vh = VT + (size_t)bh * 64 * 2048;
  const int q0 = qblk * 64 + wid * 16;

  bf16x8 qf[2];
#pragma unroll
  for (int kc = 0; kc < 2; ++kc)
    qf[kc] = *(const bf16x8*)(Sq + (size_t)(q0 + rl) * 3072 + kc * 32 + kg * 8);

  f32x4 O[4] = {};
  float m_j[4] = {-INFINITY, -INFINITY, -INFINITY, -INFINITY};
  float l_j[4] = {0.f, 0.f, 0.f, 0.f};

  for (int kt = 0; kt <= qblk; ++kt) {
    f32x4 sb[4] = {};
#pragma unroll
    for (int nb = 0; nb < 4; ++nb)
#pragma unroll
      for (int kc = 0; kc < 2; ++kc) {
        bf16x8 kf = *(const bf16x8*)(Sk + (size_t)(kt * 64 + nb * 16 + rl) * 3072 + kc * 32 + kg * 8);
        sb[nb] = MFMA16(qf[kc], kf, sb[nb]);
      }

    float sc[4][4];
    float mx[4] = {-INFINITY, -INFINITY, -INFINITY, -INFINITY};
    const int rowq = q0 + kg * 4;
#pragma unroll
    for (int nb = 0; nb < 4; ++nb) {
      int col = kt * 64 + nb * 16 + rl;
#pragma unroll
      for (int j = 0; j < 4; ++j) {
        float v = sb[nb][j] * 0.125f;
        v = (col <= rowq + j) ? v : -INFINITY;
        sc[nb][j] = v;
        mx[j] = fmaxf(mx[j], v);
      }
    }
#pragma unroll
    for (int off = 1; off < 16; off <<= 1)
#pragma unroll
      for (int j = 0; j < 4; ++j)
        mx[j] = fmaxf(mx[j], __shfl_xor(mx[j], off));

    float scl[4], psum[4];
#pragma unroll
    for (int j = 0; j < 4; ++j) {
      float mn = fmaxf(m_j[j], mx[j]);
      scl[j] = __expf(m_j[j] - mn);  // exp(-inf)=0 on first tile
      m_j[j] = mn;
      psum[j] = 0.f;
    }
#pragma unroll
    for (int nb = 0; nb < 4; ++nb)
#pragma unroll
      for (int j = 0; j < 4; ++j) {
        float p = __expf(sc[nb][j] - m_j[j]);  // -inf -> 0
        psum[j] += p;
        P[wid][kg * 4 + j][nb * 16 + rl] = f2bf(p);
      }
#pragma unroll
    for (int off = 1; off < 16; off <<= 1)
#pragma unroll
      for (int j = 0; j < 4; ++j)
        psum[j] += __shfl_xor(psum[j], off);
#pragma unroll
    for (int j = 0; j < 4; ++j) l_j[j] = l_j[j] * scl[j] + psum[j];
#pragma unroll
    for (int d = 0; d < 4; ++d)
#pragma unroll
      for (int j = 0; j < 4; ++j) O[d][j] *= scl[j];

    // No __syncthreads: P tile is per-wave; same-wave LDS write->read is
    // ordered by compiler-inserted lgkmcnt waits.
#pragma unroll
    for (int kc = 0; kc < 2; ++kc) {
      bf16x8 pf = *(const bf16x8*)(&P[wid][rl][kc * 32 + kg * 8]);
#pragma unroll
      for (int d = 0; d < 4; ++d) {
        bf16x8 vf = *(const bf16x8*)(Vh + (size_t)(d * 16 + rl) * 2048 + kt * 64 + kc * 32 + kg * 8);
        O[d] = MFMA16(pf, vf, O[d]);
      }
    }
  }

#pragma unroll
  for (int d = 0; d < 4; ++d)
#pragma unroll
    for (int j = 0; j < 4; ++j) {
      float val = O[d][j] / l_j[j];
      size_t q = (size_t)b * 2048 + q0 + kg * 4 + j;
      Y[q * 1024 + h * 64 + d * 16 + rl] = f2bf(val);
    }
}

// ---------------------------------------------------------------------------
extern "C" void kernel_launch(void* const* d_in, const int* in_sizes, int n_in,
                              void* d_out, int out_size, void* d_ws, size_t ws_size,
                              hipStream_t stream) {
  const float* x = (const float*)d_in[0];       // [8192][1024] fp32
  const float* w_attn = (const float*)d_in[1];  // [1024][3072] fp32
  const float* w_proj = (const float*)d_in[2];  // [1024][1024] fp32
  float* out = (float*)d_out;                   // [8192][1024] fp32

  u16* S = (u16*)d_ws;                          // 8192*3072 bf16
  u16* WT1 = S + (size_t)8192 * 3072;           // 3072*1024
  u16* WT2 = WT1 + (size_t)3072 * 1024;         // 1024*1024
  u16* VT = WT2 + (size_t)1024 * 1024;          // 64*64*2048
  u16* Y = VT + (size_t)64 * 64 * 2048;         // 8192*1024
  u16* XB = Y + (size_t)8192 * 1024;            // 8192*1024
  // total: 54,525,952 u16 = 109 MB of ws

  cvt_f32_bf16<<<8192, 256, 0, stream>>>(x, XB);  // 8192*1024/4/256 = 8192
  transpose_w<<<dim3(3072 / 64, 1024 / 64), 256, 0, stream>>>(w_attn, WT1, 1024, 3072);
  transpose_w<<<dim3(1024 / 64, 1024 / 64), 256, 0, stream>>>(w_proj, WT2, 1024, 1024);
  gemm_bt<false><<<dim3(3072 / 128, 8192 / 128), 256, 0, stream>>>(XB, WT1, S, 8192, 3072, 1024);
  transpose_v<<<dim3(32, 64), 256, 0, stream>>>(S, VT);
  attn<<<dim3(32, 64), 256, 0, stream>>>(S, VT, Y);
  gemm_bt<true><<<dim3(1024 / 128, 8192 / 128), 256, 0, stream>>>(Y, WT2, out, 8192, 1024, 1024);
}

// Round 3
// 342.344 us; speedup vs baseline: 1.8425x; 1.8425x over previous
//
#include <hip/hip_runtime.h>
#include <math.h>

typedef unsigned short u16;
typedef unsigned int u32;
typedef __bf16 bf16x8 __attribute__((ext_vector_type(8)));
typedef float f32x4 __attribute__((ext_vector_type(4)));
typedef u16 u16x4 __attribute__((ext_vector_type(4)));
typedef u16 u16x8 __attribute__((ext_vector_type(8)));

#define MFMA16(a, b, c) __builtin_amdgcn_mfma_f32_16x16x32_bf16((a), (b), (c), 0, 0, 0)

#define GLL16(g, l)                                                   \
  __builtin_amdgcn_global_load_lds(                                   \
      (const __attribute__((address_space(1))) void*)(g),             \
      (__attribute__((address_space(3))) void*)(l), 16, 0, 0)

__device__ __forceinline__ u16 f2bf(float f) {
  __bf16 h = (__bf16)f;  // native RNE cvt (m240: scalar cast beats asm cvt_pk)
  return __builtin_bit_cast(u16, h);
}

// ---------------------------------------------------------------------------
// fp32 -> bf16 elementwise convert
// ---------------------------------------------------------------------------
__global__ __launch_bounds__(256) void cvt_f32_bf16(const float* __restrict__ in,
                                                    u16* __restrict__ out) {
  size_t i = ((size_t)blockIdx.x * 256 + threadIdx.x) * 4;
  float4 v = *(const float4*)(in + i);
  u16x4 o;
  o[0] = f2bf(v.x); o[1] = f2bf(v.y); o[2] = f2bf(v.z); o[3] = f2bf(v.w);
  *(u16x4*)(out + i) = o;
}

// ---------------------------------------------------------------------------
// fp32 in[R][Cn] -> bf16 out[Cn][R] (64x64 tiles, fused convert+transpose)
// ---------------------------------------------------------------------------
__global__ __launch_bounds__(256) void transpose_w(const float* __restrict__ in,
                                                   u16* __restrict__ out,
                                                   int R, int Cn) {
  __shared__ u16 tile[64][72];
  const int t = threadIdx.x;
  const int tr = blockIdx.y * 64;
  const int tc = blockIdx.x * 64;
#pragma unroll
  for (int p = 0; p < 4; ++p) {
    int chunk = p * 256 + t;
    int r = chunk >> 4, cq = chunk & 15;
    float4 v = *(const float4*)(in + (size_t)(tr + r) * Cn + tc + cq * 4);
    tile[r][cq * 4 + 0] = f2bf(v.x);
    tile[r][cq * 4 + 1] = f2bf(v.y);
    tile[r][cq * 4 + 2] = f2bf(v.z);
    tile[r][cq * 4 + 3] = f2bf(v.w);
  }
  __syncthreads();
#pragma unroll
  for (int p = 0; p < 2; ++p) {
    int chunk = p * 256 + t;
    int c = chunk >> 3, rg = chunk & 7;
    u16x8 v;
#pragma unroll
    for (int i = 0; i < 8; ++i) v[i] = tile[rg * 8 + i][c];
    *(u16x8*)(out + (size_t)(tc + c) * R + tr + rg * 8) = v;
  }
}

// ---------------------------------------------------------------------------
// V-part transpose (bf16 S): VT[(b*16+h)*64 + d][l] = S[b*2048+l][2048+h*64+d]
// ---------------------------------------------------------------------------
__global__ __launch_bounds__(256) void transpose_v(const u16* __restrict__ S,
                                                   u16* __restrict__ VT) {
  __shared__ u16 tile[64][72];
  const int t = threadIdx.x;
  const int lt = blockIdx.x;
  const int bh = blockIdx.y;
  const int b = bh >> 4, h = bh & 15;
  const u16* src = S + ((size_t)b * 2048 + (size_t)lt * 64) * 3072 + 2048 + h * 64;
  u16* dst = VT + (size_t)bh * 64 * 2048 + (size_t)lt * 64;
#pragma unroll
  for (int p = 0; p < 2; ++p) {
    int chunk = p * 256 + t;
    int r = chunk >> 3, cg = chunk & 7;
    u16x8 v = *(const u16x8*)(src + (size_t)r * 3072 + cg * 8);
    *(u16x8*)(&tile[r][cg * 8]) = v;
  }
  __syncthreads();
#pragma unroll
  for (int p = 0; p < 2; ++p) {
    int chunk = p * 256 + t;
    int d = chunk >> 3, rg = chunk & 7;
    u16x8 v;
#pragma unroll
    for (int i = 0; i < 8; ++i) v[i] = tile[rg * 8 + i][d];
    *(u16x8*)(dst + (size_t)d * 2048 + rg * 8) = v;
  }
}

// ---------------------------------------------------------------------------
// GEMM: C[M][N] = A[M][K] @ B, BT = B^T as [N][K]. 128x128 tile, BK=64.
// ---------------------------------------------------------------------------
template <bool OUTF32>
__global__ __launch_bounds__(256, 2) void gemm_bt(const u16* __restrict__ A,
                                                  const u16* __restrict__ BT,
                                                  void* __restrict__ Cp,
                                                  int M, int N, int K) {
  __shared__ u16 As[128 * 64];
  __shared__ u16 Bs[128 * 64];
  const int tid = threadIdx.x;
  const int lane = tid & 63;
  const int wid = tid >> 6;
  const int wr = wid >> 1, wc = wid & 1;
  const int rl = lane & 15, kg = lane >> 4;
  const size_t rowA0 = (size_t)blockIdx.y * 128;
  const size_t rowB0 = (size_t)blockIdx.x * 128;

  const int r_st = tid >> 3;
  const int cg_st = tid & 7;

  f32x4 acc[4][4] = {};

  for (int kb = 0; kb < K; kb += 64) {
    __syncthreads();
#pragma unroll
    for (int it = 0; it < 4; ++it) {
      int r = it * 32 + r_st;
      int cgs = cg_st ^ (r & 7);
      GLL16(A + (rowA0 + r) * K + kb + cgs * 8, As + (size_t)r * 64 + cg_st * 8);
      GLL16(BT + (rowB0 + r) * K + kb + cgs * 8, Bs + (size_t)r * 64 + cg_st * 8);
    }
    __syncthreads();

    bf16x8 af[2][4], bfr[2][4];
#pragma unroll
    for (int kk = 0; kk < 2; ++kk) {
      int c8 = kk * 4 + kg;
#pragma unroll
      for (int m = 0; m < 4; ++m) {
        int ra = wr * 64 + m * 16 + rl;
        af[kk][m] = *(const bf16x8*)(As + (size_t)ra * 64 + (size_t)((c8 ^ (ra & 7)) * 8));
        int rb = wc * 64 + m * 16 + rl;
        bfr[kk][m] = *(const bf16x8*)(Bs + (size_t)rb * 64 + (size_t)((c8 ^ (rb & 7)) * 8));
      }
    }
#pragma unroll
    for (int kk = 0; kk < 2; ++kk)
#pragma unroll
      for (int m = 0; m < 4; ++m)
#pragma unroll
        for (int n = 0; n < 4; ++n)
          acc[m][n] = MFMA16(af[kk][m], bfr[kk][n], acc[m][n]);
  }

#pragma unroll
  for (int m = 0; m < 4; ++m)
#pragma unroll
    for (int n = 0; n < 4; ++n)
#pragma unroll
      for (int j = 0; j < 4; ++j) {
        size_t r = rowA0 + wr * 64 + m * 16 + kg * 4 + j;
        size_t c = rowB0 + wc * 64 + n * 16 + rl;
        if constexpr (OUTF32)
          ((float*)Cp)[r * N + c] = acc[m][n][j];
        else
          ((u16*)Cp)[r * N + c] = f2bf(acc[m][n][j]);
      }
}

// ---------------------------------------------------------------------------
// Causal flash attention, paired q-tiles for load balance.
// grid: x = g (16 pairs), y = bh (64). Block g owns q-tiles {g, 31-g}.
// 4 waves x 16 q-rows per tile. K/V cooperatively staged in LDS,
// double-buffered (global_load_lds), both-sides XOR swizzle (rule #21).
// ---------------------------------------------------------------------------
__global__ __launch_bounds__(256) void attn(const u16* __restrict__ S,
                                            const u16* __restrict__ VT,
                                            u16* __restrict__ Y) {
  __shared__ u16 Ks[2][64 * 64];  // 16 KB
  __shared__ u16 Vs[2][64 * 64];  // 16 KB
  __shared__ u16 P[4][16][72];    // 9 KB, per-wave P tile (padded)
  const int g = blockIdx.x;       // 0..15
  const int t1 = 31 - g;          // 31..16
  const int bh = blockIdx.y;
  const int b = bh >> 4, h = bh & 15;
  const int tid = threadIdx.x, lane = tid & 63, wid = tid >> 6;
  const int rl = lane & 15, kg = lane >> 4;
  const u16* Sq = S + (size_t)b * 2048 * 3072 + h * 64;
  const u16* Sk = Sq + 1024;
  const u16* Vh = VT + (size_t)bh * 64 * 2048;

  const int sr = tid >> 3;  // staging row 0..31 (plus +32 on 2nd issue)
  const int scg = tid & 7;  // staging chunk

  const int q0[2] = {g * 64 + wid * 16, t1 * 64 + wid * 16};
  const int tsel[2] = {g, t1};

  bf16x8 qf[2][2];
#pragma unroll
  for (int grp = 0; grp < 2; ++grp)
#pragma unroll
    for (int kc = 0; kc < 2; ++kc)
      qf[grp][kc] = *(const bf16x8*)(Sq + (size_t)(q0[grp] + rl) * 3072 + kc * 32 + kg * 8);

  f32x4 O[2][4] = {};
  float mj[2][4], lj[2][4];
#pragma unroll
  for (int grp = 0; grp < 2; ++grp)
#pragma unroll
    for (int j = 0; j < 4; ++j) { mj[grp][j] = -INFINITY; lj[grp][j] = 0.f; }

  const float SC = 0.125f * 1.44269504088896f;  // /sqrt(64) * log2(e)

#define STAGE(buf, kt)                                                          \
  {                                                                             \
    _Pragma("unroll") for (int it = 0; it < 2; ++it) {                          \
      int r = it * 32 + sr;                                                     \
      int cs = scg ^ (r & 7); /* inverse-swizzled global source */              \
      GLL16(Sk + (size_t)((kt) * 64 + r) * 3072 + cs * 8,                       \
            &Ks[buf][r * 64 + scg * 8]);                                        \
      GLL16(Vh + (size_t)r * 2048 + (kt) * 64 + cs * 8,                         \
            &Vs[buf][r * 64 + scg * 8]);                                        \
    }                                                                           \
  }

  STAGE(0, 0);
  __syncthreads();  // drains vmcnt(0)

  for (int kt = 0; kt <= t1; ++kt) {
    const int cur = kt & 1;
    if (kt < t1) STAGE(cur ^ 1, kt + 1);  // async prefetch over compute

    const u16* Ksb = Ks[cur];
    const u16* Vsb = Vs[cur];

#pragma unroll
    for (int grp = 0; grp < 2; ++grp) {
      if (grp == 0 && kt > g) continue;  // block-uniform

      // ---- QK^T (swizzled ds_read fragments) ----
      f32x4 sb[4] = {};
#pragma unroll
      for (int nb = 0; nb < 4; ++nb)
#pragma unroll
        for (int kc = 0; kc < 2; ++kc) {
          bf16x8 kf = *(const bf16x8*)(Ksb + (size_t)(nb * 16 + rl) * 64 +
                                       (size_t)(((kc * 4 + kg) ^ (rl & 7)) * 8));
          sb[nb] = MFMA16(qf[grp][kc], kf, sb[nb]);
        }

      // ---- online softmax (base-2 domain, diagonal-only mask) ----
      const bool diag = (kt == tsel[grp]);
      const int rowq = q0[grp] + kg * 4;
      float sc[4][4];
      float mx4[4] = {mj[grp][0], mj[grp][1], mj[grp][2], mj[grp][3]};
#pragma unroll
      for (int nb = 0; nb < 4; ++nb) {
        int col = kt * 64 + nb * 16 + rl;
#pragma unroll
        for (int j = 0; j < 4; ++j) {
          float v = sb[nb][j] * SC;
          if (diag) v = (col <= rowq + j) ? v : -INFINITY;
          sc[nb][j] = v;
          mx4[j] = fmaxf(mx4[j], v);
        }
      }
#pragma unroll
      for (int off = 1; off < 16; off <<= 1)
#pragma unroll
        for (int j = 0; j < 4; ++j)
          mx4[j] = fmaxf(mx4[j], __shfl_xor(mx4[j], off));

      float scl[4], ps[4];
#pragma unroll
      for (int j = 0; j < 4; ++j) {
        scl[j] = exp2f(mj[grp][j] - mx4[j]);  // exp2(-inf)=0 first tile
        mj[grp][j] = mx4[j];
        ps[j] = 0.f;
      }
#pragma unroll
      for (int nb = 0; nb < 4; ++nb)
#pragma unroll
        for (int j = 0; j < 4; ++j) {
          float p = exp2f(sc[nb][j] - mj[grp][j]);  // -inf -> 0
          ps[j] += p;
          P[wid][kg * 4 + j][nb * 16 + rl] = f2bf(p);
        }
#pragma unroll
      for (int off = 1; off < 16; off <<= 1)
#pragma unroll
        for (int j = 0; j < 4; ++j)
          ps[j] += __shfl_xor(ps[j], off);
#pragma unroll
      for (int j = 0; j < 4; ++j) lj[grp][j] = lj[grp][j] * scl[j] + ps[j];
#pragma unroll
      for (int d = 0; d < 4; ++d)
#pragma unroll
        for (int j = 0; j < 4; ++j) O[grp][d][j] *= scl[j];

      // ---- PV (P per-wave LDS roundtrip; V from swizzled LDS) ----
#pragma unroll
      for (int kc = 0; kc < 2; ++kc) {
        bf16x8 pf = *(const bf16x8*)(&P[wid][rl][kc * 32 + kg * 8]);
#pragma unroll
        for (int d = 0; d < 4; ++d) {
          bf16x8 vf = *(const bf16x8*)(Vsb + (size_t)(d * 16 + rl) * 64 +
                                       (size_t)(((kc * 4 + kg) ^ (rl & 7)) * 8));
          O[grp][d] = MFMA16(pf, vf, O[grp][d]);
        }
      }
    }
    __syncthreads();  // drain staged loads + protect buf reuse
  }

#pragma unroll
  for (int grp = 0; grp < 2; ++grp)
#pragma unroll
    for (int j = 0; j < 4; ++j) {
      float inv = 1.0f / lj[grp][j];
#pragma unroll
      for (int d = 0; d < 4; ++d) {
        float val = O[grp][d][j] * inv;
        size_t q = (size_t)b * 2048 + q0[grp] + kg * 4 + j;
        Y[q * 1024 + h * 64 + d * 16 + rl] = f2bf(val);
      }
    }
#undef STAGE
}

// ---------------------------------------------------------------------------
extern "C" void kernel_launch(void* const* d_in, const int* in_sizes, int n_in,
                              void* d_out, int out_size, void* d_ws, size_t ws_size,
                              hipStream_t stream) {
  const float* x = (const float*)d_in[0];       // [8192][1024] fp32
  const float* w_attn = (const float*)d_in[1];  // [1024][3072] fp32
  const float* w_proj = (const float*)d_in[2];  // [1024][1024] fp32
  float* out = (float*)d_out;                   // [8192][1024] fp32

  u16* S = (u16*)d_ws;                          // 8192*3072 bf16
  u16* WT1 = S + (size_t)8192 * 3072;           // 3072*1024
  u16* WT2 = WT1 + (size_t)3072 * 1024;         // 1024*1024
  u16* VT = WT2 + (size_t)1024 * 1024;          // 64*64*2048
  u16* Y = VT + (size_t)64 * 64 * 2048;         // 8192*1024
  u16* XB = Y + (size_t)8192 * 1024;            // 8192*1024

  cvt_f32_bf16<<<8192, 256, 0, stream>>>(x, XB);
  transpose_w<<<dim3(3072 / 64, 1024 / 64), 256, 0, stream>>>(w_attn, WT1, 1024, 3072);
  transpose_w<<<dim3(1024 / 64, 1024 / 64), 256, 0, stream>>>(w_proj, WT2, 1024, 1024);
  gemm_bt<false><<<dim3(3072 / 128, 8192 / 128), 256, 0, stream>>>(XB, WT1, S, 8192, 3072, 1024);
  transpose_v<<<dim3(32, 64), 256, 0, stream>>>(S, VT);
  attn<<<dim3(16, 64), 256, 0, stream>>>(S, VT, Y);
  gemm_bt<true><<<dim3(1024 / 128, 8192 / 128), 256, 0, stream>>>(Y, WT2, out, 8192, 1024, 1024);
}